// Round 15
// baseline (125.392 us; speedup 1.0000x reference)
//
#include <hip/hip_runtime.h>
#include <hip/hip_bf16.h>

#define M 10000
#define TOP_K 2000
#define NW 157            // keep words (full problem)
#define NMS_T 0.7f
#define WCAP 64           // eager window: words < 64, rows < 4096
#define MROWS 4096
#define NBK 4096          // score buckets
#define BKCAP 64          // slots per bucket (input max ~13)
#define NSEG 16           // edge-list segments (contention spreading)
#define SEGSZ 640
#define ECAP (NSEG * SEGSZ)        // 10240
#define NTILE (WCAP * (WCAP + 1) / 2)   // 2080 upper-tri tiles

typedef unsigned long long ull;

// ---- ws layout (bytes) ----
#define OFF_ORD    0
#define OFF_SX1    40000
#define OFF_SY1    80000
#define OFF_SX2    120000
#define OFF_SY2    160000
#define OFF_AREA   200000
#define OFF_ECNT   240000                          // 16 * 4 B
#define OFF_BUF    240064                          // NBK*BKCAP*8 = 2 MB
#define OFF_META   (OFF_BUF + (size_t)NBK * BKCAP * 8)
#define OFF_EWORD  (OFF_META + ECAP * 4)
#define NEED       (OFF_EWORD + (size_t)ECAP * 8)  // ~2.46 MB << ws_size

// ---------------- Kernel 1: fused sort (zero+scatter+prefix+bucket-rank) --------
// Single block, cnt/pre in LDS. Bucket b monotone in descending score; in-bucket
// rank by full key (score desc, idx asc) -> deterministic == jnp.argsort(-scores).
__global__ __launch_bounds__(1024) void k_sort(const float* __restrict__ prop,
                                               unsigned* __restrict__ ecnt,
                                               ull* __restrict__ buf,
                                               int* __restrict__ ord,
                                               float* __restrict__ sx1, float* __restrict__ sy1,
                                               float* __restrict__ sx2, float* __restrict__ sy2,
                                               float* __restrict__ sarea) {
    __shared__ unsigned cnt[NBK];    // 16 KB
    __shared__ unsigned pre[NBK];    // 16 KB
    __shared__ unsigned wsum[16];
    const int tid = threadIdx.x;
    const int lane = tid & 63, w = tid >> 6;

#pragma unroll
    for (int k = 0; k < NBK / 1024; ++k) cnt[k * 1024 + tid] = 0u;
    if (tid < NSEG) ecnt[tid] = 0u;          // zero edge counters for k_mask
    __syncthreads();

    // scatter (LDS atomics)
#pragma unroll
    for (int k = 0; k < 10; ++k) {
        int e = k * 1024 + tid;
        if (e < M) {
            float s = prop[e * 6 + 5];
            int t = (int)(s * 4096.0f);
            int b = 4095 - (t > 4095 ? 4095 : t);
            unsigned slot = atomicAdd(&cnt[b], 1u);
            if (slot < BKCAP)
                buf[(size_t)b * BKCAP + slot] = (((ull)(~__float_as_uint(s))) << 16) | (unsigned)e;
        }
    }
    __syncthreads();

    // exclusive prefix over 4096 buckets (4 bins/thread)
    unsigned c0 = cnt[tid * 4 + 0], c1 = cnt[tid * 4 + 1];
    unsigned c2 = cnt[tid * 4 + 2], c3 = cnt[tid * 4 + 3];
    unsigned s = c0 + c1 + c2 + c3;
    unsigned inc = s;
    for (int off = 1; off < 64; off <<= 1) {
        unsigned n = __shfl_up(inc, off, 64);
        if (lane >= off) inc += n;
    }
    if (lane == 63) wsum[w] = inc;
    __syncthreads();
    unsigned wb = 0;
#pragma unroll
    for (int q = 0; q < 16; ++q) wb += (q < w) ? wsum[q] : 0u;
    unsigned ex = wb + inc - s;
    pre[tid * 4 + 0] = ex;
    pre[tid * 4 + 1] = ex + c0;
    pre[tid * 4 + 2] = ex + c0 + c1;
    pre[tid * 4 + 3] = ex + c0 + c1 + c2;
    __syncthreads();

    // in-bucket full-key rank + direct gather (4 buckets/thread)
#pragma unroll
    for (int k = 0; k < 4; ++k) {
        int b = tid * 4 + k;
        unsigned c = cnt[b]; if (c > BKCAP) c = BKCAP;
        unsigned p0 = pre[b];
        const ull* bb = buf + (size_t)b * BKCAP;
        for (unsigned i = 0; i < c; ++i) {
            ull ki = bb[i];
            unsigned rank = 0;
            for (unsigned j = 0; j < c; ++j) rank += (bb[j] < ki) ? 1u : 0u;
            unsigned q = p0 + rank;
            int o = (int)(ki & 0xFFFFull);
            ord[q] = o;
            float x1 = prop[o * 6 + 1], y1 = prop[o * 6 + 2];
            float x2 = prop[o * 6 + 3], y2 = prop[o * 6 + 4];
            sx1[q] = x1; sy1[q] = y1; sx2[q] = x2; sy2[q] = y2;
            sarea[q] = (x2 - x1) * (y2 - y1);
        }
    }
}

// ---------------- Kernel 2: edge extraction, batched segmented append ------------
// 1D triangular grid (2080 blocks). Lane keeps its own row's ballot word; ONE
// atomicAdd per tile-with-edges, spread over 16 segment counters.
__global__ __launch_bounds__(64) void k_mask(const float* __restrict__ sx1, const float* __restrict__ sy1,
                                             const float* __restrict__ sx2, const float* __restrict__ sy2,
                                             const float* __restrict__ sarea,
                                             unsigned* __restrict__ ecnt,
                                             unsigned* __restrict__ meta,
                                             ull* __restrict__ eword) {
    int t = blockIdx.x, ci = 0, rl = WCAP;
    while (t >= rl) { t -= rl; --rl; ++ci; }
    const int cj = ci + t;
    const int lane = threadIdx.x;
    const int j = cj * 64 + lane;
    const float jx1 = sx1[j], jy1 = sy1[j], jx2 = sx2[j], jy2 = sy2[j], ja = sarea[j];
    const int i0 = ci * 64;
    const bool diag = (ci == cj);
    ull myw = 0ull;                          // row (i0+lane)'s word for column cj
    for (int r = 0; r < 64; ++r) {
        const int i = i0 + r;
        float ix1 = sx1[i], iy1 = sy1[i], ix2 = sx2[i], iy2 = sy2[i], ia = sarea[i];
        float iw = fminf(ix2, jx2) - fmaxf(ix1, jx1); iw = fmaxf(iw, 0.f);
        float ih = fminf(iy2, jy2) - fmaxf(iy1, jy1); ih = fmaxf(ih, 0.f);
        float inter = iw * ih;
        float iou = inter / (ia + ja - inter + 1e-8f);
        bool bit = (iou > NMS_T) && (!diag || (j > i));
        ull wv = __ballot(bit);
        myw = (lane == r) ? wv : myw;
    }
    ull nzm = __ballot(myw != 0ull);
    int nz = __popcll(nzm);
    if (nz) {
        const int seg = blockIdx.x & (NSEG - 1);
        unsigned base = 0;
        if (lane == 0) base = atomicAdd(&ecnt[seg], (unsigned)nz);
        base = (unsigned)__shfl((int)base, 0, 64);
        if (myw) {
            ull lt = (lane == 0) ? 0ull : (~0ull >> (64 - lane));
            unsigned slot = base + (unsigned)__popcll(nzm & lt);
            if (slot < SEGSZ) {
                meta[seg * SEGSZ + slot] = ((unsigned)(i0 + lane) << 6) | (unsigned)cj;
                eword[seg * SEGSZ + slot] = myw;
            }
        }
    }
}

// ---------------- Kernel 3: fixpoint NMS + select, fused ----------------
__device__ __forceinline__ ull init_keep_word(int w) {
    if (w >= NW) return 0ull;
    int rem = M - w * 64;
    if (rem >= 64) return ~0ull;
    if (rem <= 0) return 0ull;
    return (~0ull) >> (64 - rem);
}

__global__ __launch_bounds__(512) void k_nms(const unsigned* __restrict__ ecnt,
                                             const unsigned* __restrict__ meta,
                                             const ull* __restrict__ eword,
                                             const float* __restrict__ sx1, const float* __restrict__ sy1,
                                             const float* __restrict__ sx2, const float* __restrict__ sy2,
                                             const float* __restrict__ sarea,
                                             const int* __restrict__ ord,
                                             const float* __restrict__ prop,
                                             float* __restrict__ out) {
    __shared__ unsigned s_meta[ECAP];       // 40 KB
    __shared__ ull s_w[ECAP];               // 80 KB
    __shared__ ull aw[64], kill[64];
    __shared__ ull s_keep[NW];
    __shared__ int wcnt[NW];
    __shared__ unsigned segoff[NSEG + 1];
    __shared__ int s_flag, s_stop, s_total, s_ovf;

    const int tid = threadIdx.x;

    if (tid == 0) {
        unsigned acc = 0; int ovf = 0;
        for (int g = 0; g < NSEG; ++g) {
            unsigned c = ecnt[g];
            if (c > SEGSZ) { ovf = 1; c = SEGSZ; }
            segoff[g] = acc; acc += c;
        }
        segoff[NSEG] = acc; s_ovf = ovf;
    }
    __syncthreads();

    if (!s_ovf) {
        // ---------- fast path: stage edges, fixpoint ----------
        for (int g = 0; g < NSEG; ++g) {
            unsigned b0 = segoff[g], c = segoff[g + 1] - b0;
            for (unsigned e = tid; e < c; e += 512) {
                s_meta[b0 + e] = meta[g * SEGSZ + e];
                s_w[b0 + e]    = eword[g * SEGSZ + e];
            }
        }
        const unsigned ne = segoff[NSEG];
        if (tid < 64) aw[tid] = ~0ull;       // rows 0..4095 all valid
        __syncthreads();
        int rounds = 0;
        while (true) {
            if (tid < 64) kill[tid] = 0ull;
            if (tid == 0) s_flag = 0;
            __syncthreads();
            for (unsigned e = tid; e < ne; e += 512) {
                unsigned m = s_meta[e];
                unsigned i = m >> 6, cj = m & 63u;
                if ((aw[i >> 6] >> (i & 63)) & 1ull) atomicOr(&kill[cj], s_w[e]);
            }
            __syncthreads();
            if (tid < 64) {
                ull na = ~kill[tid];
                if (na != aw[tid]) { aw[tid] = na; s_flag = 1; }
            }
            __syncthreads();
            if (!s_flag || ++rounds > 4100) break;
        }
        // stop word (first word where kept prefix >= TOP_K)
        if (tid < 64) {
            int c = __popcll(aw[tid]); int inc = c;
            for (int off = 1; off < 64; off <<= 1) {
                int n = __shfl_up(inc, off, 64);
                if (tid >= off) inc += n;
            }
            ull hb = __ballot(inc >= TOP_K);
            if (tid == 0) s_stop = hb ? ((int)__builtin_ctzll(hb) + 1) : -1;
        }
        __syncthreads();
        if (s_stop >= 0) {
            if (tid < NW) s_keep[tid] = (tid < s_stop) ? aw[tid] : 0ull;
            __syncthreads();
        } else {
            // ---------- adversarial continuation (never taken on this input) -----
            if (tid < NW) s_keep[tid] = (tid < 64) ? aw[tid] : init_keep_word(tid);
            __syncthreads();
            float jx1[12], jy1[12], jx2[12], jy2[12], ja[12]; bool jv[12];
#pragma unroll
            for (int k = 0; k < 12; ++k) {
                int j = MROWS + k * 512 + tid;
                jv[k] = (j < M);
                if (jv[k]) { jx1[k]=sx1[j]; jy1[k]=sy1[j]; jx2[k]=sx2[j]; jy2[k]=sy2[j]; ja[k]=sarea[j]; }
                else       { jx1[k]=0.f; jy1[k]=0.f; jx2[k]=0.f; jy2[k]=0.f; ja[k]=0.f; }
            }
            unsigned supm = 0u;
            for (int i = 0; i < MROWS; ++i) {
                if (!((s_keep[i >> 6] >> (i & 63)) & 1ull)) continue;
                float ix1=sx1[i], iy1=sy1[i], ix2=sx2[i], iy2=sy2[i], ia=sarea[i];
#pragma unroll
                for (int k = 0; k < 12; ++k) {
                    float iw = fminf(ix2, jx2[k]) - fmaxf(ix1, jx1[k]); iw = fmaxf(iw, 0.f);
                    float ih = fminf(iy2, jy2[k]) - fmaxf(iy1, jy1[k]); ih = fmaxf(ih, 0.f);
                    float inter = iw * ih;
                    float iou = inter / (ia + ja[k] - inter + 1e-8f);
                    if (jv[k] && iou > NMS_T) supm |= (1u << k);
                }
            }
#pragma unroll
            for (int k = 0; k < 12; ++k) {
                int j = MROWS + k * 512 + tid;
                if (jv[k] && (supm & (1u << k))) atomicAnd(&s_keep[j >> 6], ~(1ull << (j & 63)));
            }
            __syncthreads();
            for (int i = MROWS; i < M; ++i) {
                if ((s_keep[i >> 6] >> (i & 63)) & 1ull) {
                    float ix1=sx1[i], iy1=sy1[i], ix2=sx2[i], iy2=sy2[i], ia=sarea[i];
#pragma unroll
                    for (int k = 0; k < 12; ++k) {
                        int j = MROWS + k * 512 + tid;
                        if (jv[k] && j > i) {
                            float iw = fminf(ix2, jx2[k]) - fmaxf(ix1, jx1[k]); iw = fmaxf(iw, 0.f);
                            float ih = fminf(iy2, jy2[k]) - fmaxf(iy1, jy1[k]); ih = fmaxf(ih, 0.f);
                            float inter = iw * ih;
                            float iou = inter / (ia + ja[k] - inter + 1e-8f);
                            if (iou > NMS_T) atomicAnd(&s_keep[j >> 6], ~(1ull << (j & 63)));
                        }
                    }
                }
                __syncthreads();
            }
        }
    } else {
        // ---------- overflow fallback: full brute NMS (never taken) ----------
        if (tid < NW) s_keep[tid] = init_keep_word(tid);
        __syncthreads();
        float jx1[20], jy1[20], jx2[20], jy2[20], ja[20]; bool jv[20];
#pragma unroll
        for (int k = 0; k < 20; ++k) {
            int j = k * 512 + tid;
            jv[k] = (j < M);
            if (jv[k]) { jx1[k]=sx1[j]; jy1[k]=sy1[j]; jx2[k]=sx2[j]; jy2[k]=sy2[j]; ja[k]=sarea[j]; }
            else       { jx1[k]=0.f; jy1[k]=0.f; jx2[k]=0.f; jy2[k]=0.f; ja[k]=0.f; }
        }
        for (int i = 0; i < M; ++i) {
            if ((s_keep[i >> 6] >> (i & 63)) & 1ull) {
                float ix1=sx1[i], iy1=sy1[i], ix2=sx2[i], iy2=sy2[i], ia=sarea[i];
#pragma unroll
                for (int k = 0; k < 20; ++k) {
                    int j = k * 512 + tid;
                    if (jv[k] && j > i) {
                        float iw = fminf(ix2, jx2[k]) - fmaxf(ix1, jx1[k]); iw = fmaxf(iw, 0.f);
                        float ih = fminf(iy2, jy2[k]) - fmaxf(iy1, jy1[k]); ih = fmaxf(ih, 0.f);
                        float inter = iw * ih;
                        float iou = inter / (ia + ja[k] - inter + 1e-8f);
                        if (iou > NMS_T) atomicAnd(&s_keep[j >> 6], ~(1ull << (j & 63)));
                    }
                }
            }
            __syncthreads();
        }
    }

    // ---------- select: stable-partition rank + gather (on LDS keep) ----------
    if (tid < NW) wcnt[tid] = __popcll(s_keep[tid]);
    __syncthreads();
    if (tid == 0) {
        int acc = 0;
        for (int w = 0; w < NW; ++w) { int c = wcnt[w]; wcnt[w] = acc; acc += c; }
        s_total = acc;
    }
    __syncthreads();
    const int total = s_total;
    for (int q = tid; q < M; q += 512) {
        int w = q >> 6, b = q & 63;
        ull kw = s_keep[w];
        int below = __popcll(kw & ((1ull << b) - 1ull));
        int kb = wcnt[w] + below;
        bool isk = (kw >> b) & 1ull;
        int rank = isk ? kb : (total + (q - kb));
        if (rank < TOP_K) {
            int o = ord[q];
            out[rank * 5 + 0] = prop[o * 6 + 0];
            out[rank * 5 + 1] = prop[o * 6 + 1];
            out[rank * 5 + 2] = prop[o * 6 + 2];
            out[rank * 5 + 3] = prop[o * 6 + 3];
            out[rank * 5 + 4] = prop[o * 6 + 4];
        }
    }
}

extern "C" void kernel_launch(void* const* d_in, const int* in_sizes, int n_in,
                              void* d_out, int out_size, void* d_ws, size_t ws_size,
                              hipStream_t stream) {
    const float* prop = (const float*)d_in[0];
    float* out = (float*)d_out;
    char* ws = (char*)d_ws;

    int*      ord   = (int*)(ws + OFF_ORD);
    float*    sx1   = (float*)(ws + OFF_SX1);
    float*    sy1   = (float*)(ws + OFF_SY1);
    float*    sx2   = (float*)(ws + OFF_SX2);
    float*    sy2   = (float*)(ws + OFF_SY2);
    float*    sarea = (float*)(ws + OFF_AREA);
    unsigned* ecnt  = (unsigned*)(ws + OFF_ECNT);
    ull*      buf   = (ull*)(ws + OFF_BUF);
    unsigned* meta  = (unsigned*)(ws + OFF_META);
    ull*      eword = (ull*)(ws + OFF_EWORD);
    // ws_size has been >= 12.8 MB in all prior rounds; NEED is ~2.46 MB.

    k_sort<<<1, 1024, 0, stream>>>(prop, ecnt, buf, ord, sx1, sy1, sx2, sy2, sarea);
    k_mask<<<NTILE, 64, 0, stream>>>(sx1, sy1, sx2, sy2, sarea, ecnt, meta, eword);
    k_nms<<<1, 512, 0, stream>>>(ecnt, meta, eword, sx1, sy1, sx2, sy2, sarea, ord, prop, out);
}

// Round 16
// 67.097 us; speedup vs baseline: 1.8688x; 1.8688x over previous
//
#include <hip/hip_runtime.h>
#include <hip/hip_bf16.h>

#define M 10000
#define TOP_K 2000
#define NW 157            // keep words (full problem)
#define NMS_T 0.7f
#define WCAP 64           // eager window: words < 64, rows < 4096
#define MROWS 4096
#define NBK 4096          // score buckets
#define BKCAP 64          // slots per bucket (input max ~13)
#define NSEG 16           // edge-list segments (contention spreading)
#define SEGSZ 640
#define ECAP (NSEG * SEGSZ)        // 10240
#define NTILE (WCAP * (WCAP + 1) / 2)   // 2080 upper-tri tiles

typedef unsigned long long ull;

// ---- ws layout (bytes) ----
#define OFF_ORD    0
#define OFF_SX1    40000
#define OFF_SY1    80000
#define OFF_SX2    120000
#define OFF_SY2    160000
#define OFF_AREA   200000
#define OFF_ECNT   240000                          // 16 * 4 B
#define OFF_CNT    240064                          // NBK * 4 = 16 KB
#define OFF_BUF    256448                          // NBK*BKCAP*8 = 2 MB
#define OFF_META   (OFF_BUF + (size_t)NBK * BKCAP * 8)
#define OFF_EWORD  (OFF_META + ECAP * 4)
#define NEED       (OFF_EWORD + (size_t)ECAP * 8)  // ~2.48 MB << ws_size

// ---------------- Kernel 0: zero counters ----------------
__global__ __launch_bounds__(1024) void k_zero(unsigned* __restrict__ cnt,
                                               unsigned* __restrict__ ecnt) {
    const int tid = threadIdx.x;
#pragma unroll
    for (int k = 0; k < NBK / 1024; ++k) cnt[k * 1024 + tid] = 0u;
    if (tid < NSEG) ecnt[tid] = 0u;
}

// ---------------- Kernel 1: bucket scatter (multi-block) ----------------
__global__ __launch_bounds__(1024) void k_scatter(const float* __restrict__ prop,
                                                  unsigned* __restrict__ cnt,
                                                  ull* __restrict__ buf) {
    int e = blockIdx.x * 1024 + threadIdx.x;
    if (e < M) {
        float s = prop[e * 6 + 5];
        int t = (int)(s * 4096.0f);
        int b = 4095 - (t > 4095 ? 4095 : t);      // ascending bucket == descending score
        unsigned slot = atomicAdd(&cnt[b], 1u);
        if (slot < BKCAP)
            buf[(size_t)b * BKCAP + slot] = (((ull)(~__float_as_uint(s))) << 16) | (unsigned)e;
    }
}

// ---------------- Kernel 2: fused prefix + in-bucket rank + gather (8 blocks) ----
// Each block redundantly computes the full 4096-bucket exclusive prefix in LDS,
// then processes its own 512 buckets. Rank by full key => deterministic output.
__global__ __launch_bounds__(512) void k_bsort(const unsigned* __restrict__ cnt,
                                               const ull* __restrict__ buf,
                                               const float* __restrict__ prop,
                                               int* __restrict__ ord,
                                               float* __restrict__ sx1, float* __restrict__ sy1,
                                               float* __restrict__ sx2, float* __restrict__ sy2,
                                               float* __restrict__ sarea) {
    __shared__ unsigned pre[NBK];      // 16 KB
    __shared__ unsigned wsum[8];
    const int tid = threadIdx.x;
    const int lane = tid & 63, w = tid >> 6;

    unsigned c8[8]; unsigned s = 0;
#pragma unroll
    for (int k = 0; k < 8; ++k) { c8[k] = cnt[tid * 8 + k]; s += c8[k]; }
    unsigned inc = s;
    for (int off = 1; off < 64; off <<= 1) {
        unsigned n = __shfl_up(inc, off, 64);
        if (lane >= off) inc += n;
    }
    if (lane == 63) wsum[w] = inc;
    __syncthreads();
    unsigned wb = 0;
#pragma unroll
    for (int q = 0; q < 8; ++q) wb += (q < w) ? wsum[q] : 0u;
    unsigned ex = wb + inc - s;
#pragma unroll
    for (int k = 0; k < 8; ++k) { pre[tid * 8 + k] = ex; ex += c8[k]; }
    __syncthreads();

    const int b = blockIdx.x * 512 + tid;
    unsigned c = cnt[b]; if (c > BKCAP) c = BKCAP;
    const unsigned p0 = pre[b];
    const ull* bb = buf + (size_t)b * BKCAP;
    for (unsigned i = 0; i < c; ++i) {
        ull ki = bb[i];
        unsigned rank = 0;
        for (unsigned j = 0; j < c; ++j) rank += (bb[j] < ki) ? 1u : 0u;
        unsigned p = p0 + rank;
        int o = (int)(ki & 0xFFFFull);
        ord[p] = o;
        float x1 = prop[o * 6 + 1], y1 = prop[o * 6 + 2];
        float x2 = prop[o * 6 + 3], y2 = prop[o * 6 + 4];
        sx1[p] = x1; sy1[p] = y1; sx2[p] = x2; sy2[p] = y2;
        sarea[p] = (x2 - x1) * (y2 - y1);
    }
}

// ---------------- Kernel 3: edge extraction, batched segmented append ------------
// 1D triangular grid (2080 blocks). Lane keeps its own row's ballot word; ONE
// atomicAdd per tile-with-edges, spread over 16 segment counters.
__global__ __launch_bounds__(64) void k_mask(const float* __restrict__ sx1, const float* __restrict__ sy1,
                                             const float* __restrict__ sx2, const float* __restrict__ sy2,
                                             const float* __restrict__ sarea,
                                             unsigned* __restrict__ ecnt,
                                             unsigned* __restrict__ meta,
                                             ull* __restrict__ eword) {
    int t = blockIdx.x, ci = 0, rl = WCAP;
    while (t >= rl) { t -= rl; --rl; ++ci; }
    const int cj = ci + t;
    const int lane = threadIdx.x;
    const int j = cj * 64 + lane;
    const float jx1 = sx1[j], jy1 = sy1[j], jx2 = sx2[j], jy2 = sy2[j], ja = sarea[j];
    const int i0 = ci * 64;
    const bool diag = (ci == cj);
    ull myw = 0ull;                          // row (i0+lane)'s word for column cj
    for (int r = 0; r < 64; ++r) {
        const int i = i0 + r;
        float ix1 = sx1[i], iy1 = sy1[i], ix2 = sx2[i], iy2 = sy2[i], ia = sarea[i];
        float iw = fminf(ix2, jx2) - fmaxf(ix1, jx1); iw = fmaxf(iw, 0.f);
        float ih = fminf(iy2, jy2) - fmaxf(iy1, jy1); ih = fmaxf(ih, 0.f);
        float inter = iw * ih;
        float iou = inter / (ia + ja - inter + 1e-8f);
        bool bit = (iou > NMS_T) && (!diag || (j > i));
        ull wv = __ballot(bit);
        myw = (lane == r) ? wv : myw;
    }
    ull nzm = __ballot(myw != 0ull);
    int nz = __popcll(nzm);
    if (nz) {
        const int seg = blockIdx.x & (NSEG - 1);
        unsigned base = 0;
        if (lane == 0) base = atomicAdd(&ecnt[seg], (unsigned)nz);
        base = (unsigned)__shfl((int)base, 0, 64);
        if (myw) {
            ull lt = (lane == 0) ? 0ull : (~0ull >> (64 - lane));
            unsigned slot = base + (unsigned)__popcll(nzm & lt);
            if (slot < SEGSZ) {
                meta[seg * SEGSZ + slot] = ((unsigned)(i0 + lane) << 6) | (unsigned)cj;
                eword[seg * SEGSZ + slot] = myw;
            }
        }
    }
}

// ---------------- Kernel 4: fixpoint NMS + select, fused ----------------
__device__ __forceinline__ ull init_keep_word(int w) {
    if (w >= NW) return 0ull;
    int rem = M - w * 64;
    if (rem >= 64) return ~0ull;
    if (rem <= 0) return 0ull;
    return (~0ull) >> (64 - rem);
}

__global__ __launch_bounds__(512) void k_nms(const unsigned* __restrict__ ecnt,
                                             const unsigned* __restrict__ meta,
                                             const ull* __restrict__ eword,
                                             const float* __restrict__ sx1, const float* __restrict__ sy1,
                                             const float* __restrict__ sx2, const float* __restrict__ sy2,
                                             const float* __restrict__ sarea,
                                             const int* __restrict__ ord,
                                             const float* __restrict__ prop,
                                             float* __restrict__ out) {
    __shared__ unsigned s_meta[ECAP];       // 40 KB
    __shared__ ull s_w[ECAP];               // 80 KB
    __shared__ ull aw[64], kill[64];
    __shared__ ull s_keep[NW];
    __shared__ int wcnt[NW];
    __shared__ unsigned segoff[NSEG + 1];
    __shared__ int s_flag, s_stop, s_total, s_ovf;

    const int tid = threadIdx.x;

    if (tid == 0) {
        unsigned acc = 0; int ovf = 0;
        for (int g = 0; g < NSEG; ++g) {
            unsigned c = ecnt[g];
            if (c > SEGSZ) { ovf = 1; c = SEGSZ; }
            segoff[g] = acc; acc += c;
        }
        segoff[NSEG] = acc; s_ovf = ovf;
    }
    __syncthreads();

    if (!s_ovf) {
        // ---------- fast path: stage edges, fixpoint ----------
        for (int g = 0; g < NSEG; ++g) {
            unsigned b0 = segoff[g], c = segoff[g + 1] - b0;
            for (unsigned e = tid; e < c; e += 512) {
                s_meta[b0 + e] = meta[g * SEGSZ + e];
                s_w[b0 + e]    = eword[g * SEGSZ + e];
            }
        }
        const unsigned ne = segoff[NSEG];
        if (tid < 64) aw[tid] = ~0ull;       // rows 0..4095 all valid
        __syncthreads();
        int rounds = 0;
        while (true) {
            if (tid < 64) kill[tid] = 0ull;
            if (tid == 0) s_flag = 0;
            __syncthreads();
            for (unsigned e = tid; e < ne; e += 512) {
                unsigned m = s_meta[e];
                unsigned i = m >> 6, cj = m & 63u;
                if ((aw[i >> 6] >> (i & 63)) & 1ull) atomicOr(&kill[cj], s_w[e]);
            }
            __syncthreads();
            if (tid < 64) {
                ull na = ~kill[tid];
                if (na != aw[tid]) { aw[tid] = na; s_flag = 1; }
            }
            __syncthreads();
            if (!s_flag || ++rounds > 4100) break;
        }
        // stop word (first word where kept prefix >= TOP_K)
        if (tid < 64) {
            int c = __popcll(aw[tid]); int inc = c;
            for (int off = 1; off < 64; off <<= 1) {
                int n = __shfl_up(inc, off, 64);
                if (tid >= off) inc += n;
            }
            ull hb = __ballot(inc >= TOP_K);
            if (tid == 0) s_stop = hb ? ((int)__builtin_ctzll(hb) + 1) : -1;
        }
        __syncthreads();
        if (s_stop >= 0) {
            if (tid < NW) s_keep[tid] = (tid < s_stop) ? aw[tid] : 0ull;
            __syncthreads();
        } else {
            // ---------- adversarial continuation (never taken on this input) -----
            if (tid < NW) s_keep[tid] = (tid < 64) ? aw[tid] : init_keep_word(tid);
            __syncthreads();
            float jx1[12], jy1[12], jx2[12], jy2[12], ja[12]; bool jv[12];
#pragma unroll
            for (int k = 0; k < 12; ++k) {
                int j = MROWS + k * 512 + tid;
                jv[k] = (j < M);
                if (jv[k]) { jx1[k]=sx1[j]; jy1[k]=sy1[j]; jx2[k]=sx2[j]; jy2[k]=sy2[j]; ja[k]=sarea[j]; }
                else       { jx1[k]=0.f; jy1[k]=0.f; jx2[k]=0.f; jy2[k]=0.f; ja[k]=0.f; }
            }
            unsigned supm = 0u;
            for (int i = 0; i < MROWS; ++i) {
                if (!((s_keep[i >> 6] >> (i & 63)) & 1ull)) continue;
                float ix1=sx1[i], iy1=sy1[i], ix2=sx2[i], iy2=sy2[i], ia=sarea[i];
#pragma unroll
                for (int k = 0; k < 12; ++k) {
                    float iw = fminf(ix2, jx2[k]) - fmaxf(ix1, jx1[k]); iw = fmaxf(iw, 0.f);
                    float ih = fminf(iy2, jy2[k]) - fmaxf(iy1, jy1[k]); ih = fmaxf(ih, 0.f);
                    float inter = iw * ih;
                    float iou = inter / (ia + ja[k] - inter + 1e-8f);
                    if (jv[k] && iou > NMS_T) supm |= (1u << k);
                }
            }
#pragma unroll
            for (int k = 0; k < 12; ++k) {
                int j = MROWS + k * 512 + tid;
                if (jv[k] && (supm & (1u << k))) atomicAnd(&s_keep[j >> 6], ~(1ull << (j & 63)));
            }
            __syncthreads();
            for (int i = MROWS; i < M; ++i) {
                if ((s_keep[i >> 6] >> (i & 63)) & 1ull) {
                    float ix1=sx1[i], iy1=sy1[i], ix2=sx2[i], iy2=sy2[i], ia=sarea[i];
#pragma unroll
                    for (int k = 0; k < 12; ++k) {
                        int j = MROWS + k * 512 + tid;
                        if (jv[k] && j > i) {
                            float iw = fminf(ix2, jx2[k]) - fmaxf(ix1, jx1[k]); iw = fmaxf(iw, 0.f);
                            float ih = fminf(iy2, jy2[k]) - fmaxf(iy1, jy1[k]); ih = fmaxf(ih, 0.f);
                            float inter = iw * ih;
                            float iou = inter / (ia + ja[k] - inter + 1e-8f);
                            if (iou > NMS_T) atomicAnd(&s_keep[j >> 6], ~(1ull << (j & 63)));
                        }
                    }
                }
                __syncthreads();
            }
        }
    } else {
        // ---------- overflow fallback: full brute NMS (never taken) ----------
        if (tid < NW) s_keep[tid] = init_keep_word(tid);
        __syncthreads();
        float jx1[20], jy1[20], jx2[20], jy2[20], ja[20]; bool jv[20];
#pragma unroll
        for (int k = 0; k < 20; ++k) {
            int j = k * 512 + tid;
            jv[k] = (j < M);
            if (jv[k]) { jx1[k]=sx1[j]; jy1[k]=sy1[j]; jx2[k]=sx2[j]; jy2[k]=sy2[j]; ja[k]=sarea[j]; }
            else       { jx1[k]=0.f; jy1[k]=0.f; jx2[k]=0.f; jy2[k]=0.f; ja[k]=0.f; }
        }
        for (int i = 0; i < M; ++i) {
            if ((s_keep[i >> 6] >> (i & 63)) & 1ull) {
                float ix1=sx1[i], iy1=sy1[i], ix2=sx2[i], iy2=sy2[i], ia=sarea[i];
#pragma unroll
                for (int k = 0; k < 20; ++k) {
                    int j = k * 512 + tid;
                    if (jv[k] && j > i) {
                        float iw = fminf(ix2, jx2[k]) - fmaxf(ix1, jx1[k]); iw = fmaxf(iw, 0.f);
                        float ih = fminf(iy2, jy2[k]) - fmaxf(iy1, jy1[k]); ih = fmaxf(ih, 0.f);
                        float inter = iw * ih;
                        float iou = inter / (ia + ja[k] - inter + 1e-8f);
                        if (iou > NMS_T) atomicAnd(&s_keep[j >> 6], ~(1ull << (j & 63)));
                    }
                }
            }
            __syncthreads();
        }
    }

    // ---------- select: stable-partition rank + gather (on LDS keep) ----------
    if (tid < NW) wcnt[tid] = __popcll(s_keep[tid]);
    __syncthreads();
    if (tid == 0) {
        int acc = 0;
        for (int w = 0; w < NW; ++w) { int c = wcnt[w]; wcnt[w] = acc; acc += c; }
        s_total = acc;
    }
    __syncthreads();
    const int total = s_total;
    for (int q = tid; q < M; q += 512) {
        int w = q >> 6, b = q & 63;
        ull kw = s_keep[w];
        int below = __popcll(kw & ((1ull << b) - 1ull));
        int kb = wcnt[w] + below;
        bool isk = (kw >> b) & 1ull;
        int rank = isk ? kb : (total + (q - kb));
        if (rank < TOP_K) {
            int o = ord[q];
            out[rank * 5 + 0] = prop[o * 6 + 0];
            out[rank * 5 + 1] = prop[o * 6 + 1];
            out[rank * 5 + 2] = prop[o * 6 + 2];
            out[rank * 5 + 3] = prop[o * 6 + 3];
            out[rank * 5 + 4] = prop[o * 6 + 4];
        }
    }
}

extern "C" void kernel_launch(void* const* d_in, const int* in_sizes, int n_in,
                              void* d_out, int out_size, void* d_ws, size_t ws_size,
                              hipStream_t stream) {
    const float* prop = (const float*)d_in[0];
    float* out = (float*)d_out;
    char* ws = (char*)d_ws;

    int*      ord   = (int*)(ws + OFF_ORD);
    float*    sx1   = (float*)(ws + OFF_SX1);
    float*    sy1   = (float*)(ws + OFF_SY1);
    float*    sx2   = (float*)(ws + OFF_SX2);
    float*    sy2   = (float*)(ws + OFF_SY2);
    float*    sarea = (float*)(ws + OFF_AREA);
    unsigned* ecnt  = (unsigned*)(ws + OFF_ECNT);
    unsigned* cnt   = (unsigned*)(ws + OFF_CNT);
    ull*      buf   = (ull*)(ws + OFF_BUF);
    unsigned* meta  = (unsigned*)(ws + OFF_META);
    ull*      eword = (ull*)(ws + OFF_EWORD);

    k_zero<<<1, 1024, 0, stream>>>(cnt, ecnt);
    k_scatter<<<10, 1024, 0, stream>>>(prop, cnt, buf);
    k_bsort<<<8, 512, 0, stream>>>(cnt, buf, prop, ord, sx1, sy1, sx2, sy2, sarea);
    k_mask<<<NTILE, 64, 0, stream>>>(sx1, sy1, sx2, sy2, sarea, ecnt, meta, eword);
    k_nms<<<1, 512, 0, stream>>>(ecnt, meta, eword, sx1, sy1, sx2, sy2, sarea, ord, prop, out);
}